// Round 8
// baseline (1038.042 us; speedup 1.0000x reference)
//
#include <hip/hip_runtime.h>
#include <cstddef>
#include <cstdint>

#define NN 1024
#define BB 16
#define NKNOTS 11

typedef __attribute__((ext_vector_type(8))) short short8_v;
typedef __attribute__((ext_vector_type(4))) float f32x4;
typedef __attribute__((ext_vector_type(8))) unsigned short ushort8_v;
typedef __attribute__((ext_vector_type(4))) unsigned short ushort4_v;
typedef __attribute__((ext_vector_type(4))) unsigned int uint4_v;

// ---- workspace byte offsets ----
#define WTHI_OFF  ((size_t)0)                         // 3 x 1M ushort = 6MB
#define STHI_OFF  ((size_t)6 << 20)                   // 4 x 1M ushort = 8MB
#define STLO_OFF  ((size_t)14 << 20)                  // 8MB
#define WGT_OFF   ((size_t)22 << 20)                  // 16KB bf16 swizzled W^T
#define LOSS_OFF  (((size_t)22 << 20) + 16384)
#define Z_OFF     (LOSS_OFF + 64)
#define DINV_OFF  (Z_OFF + 4096)

// ---- epilogue LDS layout (bytes) ----
#define AGGS   0        // f32 [64][68], stride 272
#define AGGH   17408    // bf16 plane [64][64], row 128B, chunk-swizzled
#define AGGL   25600
#define HH_    33792
#define HL_    41984
#define WGT_L  50176    // bf16 [64 n][128 k], row 256B, chunk^= n&15
#define HT32   66560    // packed hi/lo u32 plane [64 c][64 i]
#define PL1    0        // pred layer1 (k==11), overlays aggS
#define REDS   8192     // reg-head partials

__device__ __forceinline__ unsigned short f2bf(float x) {
  unsigned int u = __float_as_uint(x);
  return (unsigned short)((u + 0x7FFFu + ((u >> 16) & 1u)) >> 16);
}
__device__ __forceinline__ float bf2f(unsigned short h) {
  return __uint_as_float(((unsigned int)h) << 16);
}
__device__ __forceinline__ void gload16(const void* g, void* l) {
  __builtin_amdgcn_global_load_lds(
      (const __attribute__((address_space(1))) unsigned int*)g,
      (__attribute__((address_space(3))) unsigned int*)l, 16, 0, 0);
}

// -------------------------------------------------------------------------
// Kernel 1: per-row softmax denominator Z[j] and degree rsqrt dinv[j]
// -------------------------------------------------------------------------
__global__ __launch_bounds__(256) void rowstats_kernel(
    const float* __restrict__ emb, const float* __restrict__ A,
    float* __restrict__ Z, float* __restrict__ dinv)
{
  const int j = blockIdx.x;
  const int tid = threadIdx.x;
  __shared__ float ej[64];
  __shared__ float r1[256], r2[256];
  if (tid < 64) ej[tid] = emb[j * 64 + tid];
  __syncthreads();
  float zs = 0.f, as = 0.f;
  for (int i = tid; i < NN; i += 256) {
    const float4* er = (const float4*)(emb + (size_t)i * 64);
    float dot = 0.f;
#pragma unroll
    for (int q = 0; q < 16; ++q) {
      float4 e = er[q];
      dot += e.x * ej[q * 4 + 0] + e.y * ej[q * 4 + 1] +
             e.z * ej[q * 4 + 2] + e.w * ej[q * 4 + 3];
    }
    zs += expf(fmaxf(dot, 0.f));
    as += A[(size_t)j * NN + i];
  }
  r1[tid] = zs; r2[tid] = as;
  __syncthreads();
  for (int s = 128; s > 0; s >>= 1) {
    if (tid < s) { r1[tid] += r1[tid + s]; r2[tid] += r2[tid + s]; }
    __syncthreads();
  }
  if (tid == 0) {
    Z[j] = r1[0];
    dinv[j] = rsqrtf(r2[0] + 1.0f);
  }
}

// -------------------------------------------------------------------------
// Kernel 2: WT[d][i][j] = (dsteps[j][i]==d) ? W[j][i] : 0, bf16
// -------------------------------------------------------------------------
__global__ __launch_bounds__(256) void build_wt_kernel(
    const float* __restrict__ emb, const float* __restrict__ A,
    const float* __restrict__ delay, const float* __restrict__ Z,
    const float* __restrict__ dinv, unsigned short* __restrict__ WThi)
{
  const int i = blockIdx.x;
  const int tid = threadIdx.x;
  __shared__ float ei[64];
  if (tid < 64) ei[tid] = emb[i * 64 + tid];
  __syncthreads();
  const float di = dinv[i];
  for (int j = tid; j < NN; j += 256) {
    const float4* er = (const float4*)(emb + (size_t)j * 64);
    float dot = 0.f;
#pragma unroll
    for (int q = 0; q < 16; ++q) {
      float4 e = er[q];
      dot += e.x * ei[q * 4 + 0] + e.y * ei[q * 4 + 1] +
             e.z * ei[q * 4 + 2] + e.w * ei[q * 4 + 3];
    }
    float sem = expf(fmaxf(dot, 0.f)) / Z[j];
    float aji = A[(size_t)j * NN + i] + ((i == j) ? 1.f : 0.f);
    float ac = sem + dinv[j] * di * aji;
    float w = (ac > 0.001f) ? ac : 0.f;
    float dl = fminf(fmaxf(delay[(size_t)j * NN + i], 0.f), 2.f);
    int dsv = (int)rintf(dl);
#pragma unroll
    for (int d0 = 0; d0 < 3; ++d0) {
      float v = (dsv == d0) ? w : 0.f;
      WThi[((size_t)d0 << 20) + (size_t)i * NN + j] = f2bf(v);
    }
  }
}

// -------------------------------------------------------------------------
// Kernel 3: history init -> transposed bf16 hi/lo ST slices 0,1
// -------------------------------------------------------------------------
__global__ __launch_bounds__(128) void init_s_kernel(
    const float* __restrict__ ca, const float* __restrict__ W1,
    const float* __restrict__ b1, const float* __restrict__ W2,
    const float* __restrict__ b2,
    unsigned short* __restrict__ SThi, unsigned short* __restrict__ STlo)
{
  const int n = blockIdx.x;
  const int tid = threadIdx.x;
  __shared__ float l1[64];
  for (int b = 0; b < BB; ++b) {
    size_t cbase = ((size_t)(b * NN + n) * NKNOTS + 0) * 2;
    float x0 = ca[cbase + 0];
    float x1 = ca[cbase + 1];
    if (tid < 64)
      l1[tid] = fmaxf(x0 * W1[0 * 64 + tid] + x1 * W1[1 * 64 + tid] + b1[tid], 0.f);
    __syncthreads();
    float acc = b2[tid];
#pragma unroll 8
    for (int h = 0; h < 64; ++h) acc = fmaf(l1[h], W2[h * 128 + tid], acc);
    int t = tid >> 6, hh = tid & 63;
    size_t off = ((size_t)t << 20) + (size_t)(b * 64 + hh) * NN + n;
    unsigned short hv = f2bf(acc);
    SThi[off] = hv;
    STlo[off] = f2bf(acc - bf2f(hv));
    __syncthreads();
  }
}

// -------------------------------------------------------------------------
// Kernel 3b: W^T = [Wm;Ws]^T as bf16, pre-swizzled: row n (=h out), 128 k;
//            data chunk (kk>>3) stored at chunk (kk>>3)^(n&15).
// -------------------------------------------------------------------------
__global__ __launch_bounds__(256) void build_wgt_kernel(
    const float* __restrict__ Wm, const float* __restrict__ Wsm,
    unsigned short* __restrict__ wgt)
{
  int e = blockIdx.x * 256 + threadIdx.x;   // 8192 elems
  int n = e >> 7, kk = e & 127;
  float v = (kk < 64) ? Wm[kk * 64 + n] : Wsm[(kk - 64) * 64 + n];
  wgt[n * 128 + (((kk >> 3) ^ (n & 15)) << 3) + (kk & 7)] = f2bf(v);
}

// -------------------------------------------------------------------------
// Kernel 4: one scan step. LDS-FREE direct global->VGPR MFMA GEMM
//  (A = WT row-major, B = ST c-major; both frags are 16B/lane contiguous),
//  no barriers in K-loop; in-block MFMA epilogue.
//  Grid 256 = 16 i_t x 16 b; 512 thr, 8 waves = 2(wr) x 4(wc), wave 32x16.
// -------------------------------------------------------------------------
__global__ __launch_bounds__(512, 2) void step_kernel(
    const unsigned short* __restrict__ WThi,
    unsigned short* __restrict__ SThi, unsigned short* __restrict__ STlo,
    const unsigned short* __restrict__ wgt,
    const float* __restrict__ Wx, const float* __restrict__ db,
    const float* __restrict__ cb, const float* __restrict__ cc,
    const float* __restrict__ cd, const float* __restrict__ ca,
    const float* __restrict__ rW1, const float* __restrict__ rb1,
    const float* __restrict__ rW2, const float* __restrict__ rb2,
    const float* __restrict__ pW1, const float* __restrict__ pb1,
    const float* __restrict__ pW2, const float* __restrict__ pb2,
    float* __restrict__ out, float* __restrict__ loss, int k)
{
  __shared__ __align__(16) char smem[82944];
  __shared__ float sWx[128];
  __shared__ float sdb[64];

  const int tid  = threadIdx.x;
  const int lane = tid & 63;
  const int w    = tid >> 6;            // wave 0..7
  const int bid  = blockIdx.x;
  // XCD-aware decode: XCD x owns i_t in {2x, 2x+1}, all b (A L2-resident)
  const int xcd = bid & 7, idx = bid >> 3;
  const int i_t = xcd * 2 + (idx >> 4);
  const int b   = idx & 15;
  const int i0 = i_t * 64, c0 = b * 64;

  const int wr = w >> 2, wc = w & 3;    // GEMM wave tile: 32 rows x 16 cols
  const int g = lane >> 4, l15 = lane & 15;

  if (tid < 128) sWx[tid] = Wx[tid];
  else if (tid < 192) sdb[tid - 128] = db[tid - 128];

  // per-lane global fragment pointers (16B contiguous per load)
  const int rowA = i0 + wr * 32 + l15;
  const int rowB = c0 + wc * 16 + l15;
  const unsigned short* pA[3];
  const unsigned short* pB[3];
#pragma unroll
  for (int d = 0; d < 3; ++d) {
    int td = k + 1 - d; if (td < 0) td = 0;
    pA[d] = WThi + ((size_t)d << 20) + (size_t)rowA * NN + g * 8;
    pB[d] = SThi + ((size_t)(td & 3) << 20) + (size_t)rowB * NN + g * 8;
  }

  f32x4 acc[2];
  acc[0] = (f32x4){0.f, 0.f, 0.f, 0.f};
  acc[1] = (f32x4){0.f, 0.f, 0.f, 0.f};

  // ---- main GEMM: K = 3 bins x 1024, no LDS, no barriers ----
#pragma unroll 4
  for (int kk = 0; kk < 32; ++kk) {
    const int off = kk * 32;
#pragma unroll
    for (int d = 0; d < 3; ++d) {
      short8_v a0 = *(const short8_v*)(pA[d] + off);
      short8_v a1 = *(const short8_v*)(pA[d] + 16 * NN + off);
      short8_v bv = *(const short8_v*)(pB[d] + off);
      acc[0] = __builtin_amdgcn_mfma_f32_16x16x32_bf16(a0, bv, acc[0], 0, 0, 0);
      acc[1] = __builtin_amdgcn_mfma_f32_16x16x32_bf16(a1, bv, acc[1], 0, 0, 0);
    }
  }

  // ---- stage epilogue weights (async) + spill acc to aggS fp32 ----
  gload16(wgt + (size_t)tid * 8,        smem + WGT_L + tid * 16);
  gload16(wgt + 4096 + (size_t)tid * 8, smem + WGT_L + 8192 + tid * 16);

  float (*aggS)[68] = (float (*)[68])(smem + AGGS);
#pragma unroll
  for (int fr = 0; fr < 2; ++fr)
#pragma unroll
    for (int rr = 0; rr < 4; ++rr)
      aggS[wr * 32 + fr * 16 + g * 4 + rr][wc * 16 + l15] = acc[fr][rr];
  __syncthreads();

  // ---- aggS -> bf16 hi/lo planes (chunk-swizzled) ----
  {
    const int row = tid >> 3, c8 = tid & 7;
    const float* src = &aggS[row][c8 * 8];
    ushort8_v H, L;
#pragma unroll
    for (int q = 0; q < 8; ++q) {
      float f = src[q];
      unsigned short hv = f2bf(f);
      H[q] = hv; L[q] = f2bf(f - bf2f(hv));
    }
    const int pos = (c8 ^ (row & 7)) << 4;
    *(ushort8_v*)(smem + AGGH + row * 128 + pos) = H;
    *(ushort8_v*)(smem + AGGL + row * 128 + pos) = L;
  }
  // ---- stage h_k -> hH/hL planes ([i][c], chunk-swizzled) ----
  {
    const int cl = tid >> 3, ich = (tid & 7) * 8;
    size_t off = ((size_t)((k + 1) & 3) << 20) + (size_t)(c0 + cl) * NN + (i0 + ich);
    ushort8_v h8 = *(const ushort8_v*)(SThi + off);
    ushort8_v l8 = *(const ushort8_v*)(STlo + off);
#pragma unroll
    for (int q = 0; q < 8; ++q) {
      int i = ich + q;
      int byo = i * 128 + ((((cl >> 3) ^ (i & 7))) << 4) + (cl & 7) * 2;
      *(unsigned short*)(smem + HH_ + byo) = h8[q];
      *(unsigned short*)(smem + HL_ + byo) = l8[q];
    }
  }
  __syncthreads();

  // ---- MFMA mini-GEMM: pre = [agg|h](64x128) @ W^T-frags (K=128) ----
  const int mr = w & 3, nc = w >> 2;   // 4 row-frags x 2 col-pairs
  f32x4 pacc[2];
  pacc[0] = (f32x4){0.f, 0.f, 0.f, 0.f};
  pacc[1] = (f32x4){0.f, 0.f, 0.f, 0.f};
#pragma unroll
  for (int ks = 0; ks < 4; ++ks) {
    const int base = (ks < 2) ? AGGH : HH_;
    const int ks2 = ks & 1;
    const int cxa = ((ks2 * 4 + g) ^ (l15 & 7)) << 4;
    const char* ra = smem + base + (mr * 16 + l15) * 128 + cxa;
    short8_v aH = *(const short8_v*)ra;
    short8_v aL = *(const short8_v*)(ra + 8192);
#pragma unroll
    for (int fc = 0; fc < 2; ++fc) {
      const int n = (nc * 2 + fc) * 16 + l15;
      const int cxb = ((ks * 4 + g) ^ l15) << 4;
      short8_v bv = *(const short8_v*)(smem + WGT_L + n * 256 + cxb);
      pacc[fc] = __builtin_amdgcn_mfma_f32_16x16x32_bf16(aH, bv, pacc[fc], 0, 0, 0);
      pacc[fc] = __builtin_amdgcn_mfma_f32_16x16x32_bf16(aL, bv, pacc[fc], 0, 0, 0);
    }
  }

  // ---- dx@Wx + bias, tanh; write ST ring + packed hT32 plane ----
  const int ksp = (k < 11) ? k : 10;
  float hn[2][4];
#pragma unroll
  for (int rr = 0; rr < 4; ++rr) {
    int iG = i0 + mr * 16 + g * 4 + rr;
    size_t cbase = ((size_t)(b * NN + iG) * NKNOTS + ksp) * 2;
    float dx0 = cb[cbase + 0], dx1 = cb[cbase + 1];
    if (k == 11) {   // frac = 1: der = b + 2c + 3d
      dx0 += 2.f * cc[cbase + 0] + 3.f * cd[cbase + 0];
      dx1 += 2.f * cc[cbase + 1] + 3.f * cd[cbase + 1];
    }
#pragma unroll
    for (int fc = 0; fc < 2; ++fc) {
      int hcol = (nc * 2 + fc) * 16 + l15;
      float pre = pacc[fc][rr] + dx0 * sWx[hcol] + dx1 * sWx[64 + hcol] + sdb[hcol];
      hn[fc][rr] = tanhf(pre);
    }
  }
#pragma unroll
  for (int fc = 0; fc < 2; ++fc) {
    int hcol = (nc * 2 + fc) * 16 + l15;
    int iG0 = i0 + mr * 16 + g * 4;
    size_t off2 = ((size_t)((k + 2) & 3) << 20) + (size_t)(c0 + hcol) * NN + iG0;
    ushort4_v H4, L4;
    uint4_v pk;
#pragma unroll
    for (int rr = 0; rr < 4; ++rr) {
      unsigned short hv = f2bf(hn[fc][rr]);
      unsigned short lv = f2bf(hn[fc][rr] - bf2f(hv));
      H4[rr] = hv; L4[rr] = lv;
      pk[rr] = ((unsigned int)hv << 16) | lv;
    }
    *(ushort4_v*)(SThi + off2) = H4;
    *(ushort4_v*)(STlo + off2) = L4;
    const int ci = mr * 4 + g;           // i-chunk (4 i's = 16B)
    *(uint4_v*)(smem + HT32 + hcol * 256 + ((ci ^ (hcol & 15)) << 4)) = pk;
  }
  __syncthreads();

  // ---- reg head + Huber (h_new from hT32 plane) ----
  {
    const int ii = tid & 63, mg4 = (tid >> 6) * 4;
    float s0 = rb1[mg4], s1 = rb1[mg4 + 1], s2 = rb1[mg4 + 2], s3 = rb1[mg4 + 3];
#pragma unroll 8
    for (int h = 0; h < 64; ++h) {
      unsigned int v = *(const unsigned int*)(smem + HT32 + h * 256 +
                         ((((ii >> 2) ^ (h & 15))) << 4) + (ii & 3) * 4);
      float f = bf2f((unsigned short)(v >> 16)) + bf2f((unsigned short)(v & 0xffff));
      float4 wv = *(const float4*)(rW1 + h * 32 + mg4);
      s0 = fmaf(f, wv.x, s0); s1 = fmaf(f, wv.y, s1);
      s2 = fmaf(f, wv.z, s2); s3 = fmaf(f, wv.w, s3);
    }
    float4 r2v = *(const float4*)(rW2 + mg4);
    float rp = fmaxf(s0, 0.f) * r2v.x + fmaxf(s1, 0.f) * r2v.y +
               fmaxf(s2, 0.f) * r2v.z + fmaxf(s3, 0.f) * r2v.w;
    float* redS = (float*)(smem + REDS);
    redS[(tid >> 6) * 64 + ii] = rp;
    __syncthreads();
    if (tid < 64) {
      float rv = rb2[0];
#pragma unroll
      for (int m = 0; m < 8; ++m) rv += redS[m * 64 + tid];
      int iG = i0 + tid;
      size_t tb = ((size_t)(b * NN + iG) * NKNOTS + ksp) * 2;
      float tgt = ca[tb];
      if (k == 11) tgt += cb[tb] + cc[tb] + cd[tb];   // frac=1: a+b+c+d
      float dv = rv - tgt;
      float ad = fabsf(dv);
      float hub = (ad < 1.f) ? 0.5f * dv * dv : (ad - 0.5f);
      hub += __shfl_down(hub, 32);
      hub += __shfl_down(hub, 16);
      hub += __shfl_down(hub, 8);
      hub += __shfl_down(hub, 4);
      hub += __shfl_down(hub, 2);
      hub += __shfl_down(hub, 1);
      if (tid == 0) atomicAdd(loss, hub);
    }
  }

  // ---- pred head (k == 11 only) ----
  if (k == 11) {
    __syncthreads();
    const int ii = tid & 63, mg4 = (tid >> 6) * 4;
    float s0 = pb1[mg4], s1 = pb1[mg4 + 1], s2 = pb1[mg4 + 2], s3 = pb1[mg4 + 3];
#pragma unroll 8
    for (int h = 0; h < 64; ++h) {
      unsigned int v = *(const unsigned int*)(smem + HT32 + h * 256 +
                         ((((ii >> 2) ^ (h & 15))) << 4) + (ii & 3) * 4);
      float f = bf2f((unsigned short)(v >> 16)) + bf2f((unsigned short)(v & 0xffff));
      float4 wv = *(const float4*)(pW1 + h * 32 + mg4);
      s0 = fmaf(f, wv.x, s0); s1 = fmaf(f, wv.y, s1);
      s2 = fmaf(f, wv.z, s2); s3 = fmaf(f, wv.w, s3);
    }
    float* pl1 = (float*)(smem + PL1);
    pl1[ii * 32 + mg4 + 0] = fmaxf(s0, 0.f);
    pl1[ii * 32 + mg4 + 1] = fmaxf(s1, 0.f);
    pl1[ii * 32 + mg4 + 2] = fmaxf(s2, 0.f);
    pl1[ii * 32 + mg4 + 3] = fmaxf(s3, 0.f);
    __syncthreads();
#pragma unroll
    for (int rep = 0; rep < 2; ++rep) {
      int idxp = tid + rep * 512;
      if (idxp < 768) {
        int i_ = idxp / 12, o = idxp % 12;
        float s = pb2[o];
#pragma unroll
        for (int m = 0; m < 32; ++m) s = fmaf(pl1[i_ * 32 + m], pW2[m * 12 + o], s);
        out[((size_t)b * NN + (i0 + i_)) * 12 + o] = s;
      }
    }
  }
}

__global__ void finalize_kernel(const float* __restrict__ loss, float* __restrict__ out)
{
  out[196608] = loss[0] * (1.0f / 196608.0f);
}

// -------------------------------------------------------------------------
extern "C" void kernel_launch(void* const* d_in, const int* in_sizes, int n_in,
                              void* d_out, int out_size, void* d_ws, size_t ws_size,
                              hipStream_t stream)
{
  const float* A     = (const float*)d_in[0];
  const float* delay = (const float*)d_in[1];
  const float* ca    = (const float*)d_in[2];
  const float* cb    = (const float*)d_in[3];
  const float* cc    = (const float*)d_in[4];
  const float* cd    = (const float*)d_in[5];
  const float* emb   = (const float*)d_in[6];
  const float* iW1   = (const float*)d_in[7];
  const float* ib1   = (const float*)d_in[8];
  const float* iW2   = (const float*)d_in[9];
  const float* ib2   = (const float*)d_in[10];
  const float* Wm    = (const float*)d_in[11];
  const float* Wsm   = (const float*)d_in[12];
  const float* Wx    = (const float*)d_in[13];
  const float* db    = (const float*)d_in[14];
  const float* rW1   = (const float*)d_in[15];
  const float* rb1   = (const float*)d_in[16];
  const float* rW2   = (const float*)d_in[17];
  const float* rb2   = (const float*)d_in[18];
  const float* pW1   = (const float*)d_in[19];
  const float* pb1   = (const float*)d_in[20];
  const float* pW2   = (const float*)d_in[21];
  const float* pb2   = (const float*)d_in[22];

  char* wsb = (char*)d_ws;
  float* out = (float*)d_out;
  unsigned short* WThi = (unsigned short*)(wsb + WTHI_OFF);
  unsigned short* SThi = (unsigned short*)(wsb + STHI_OFF);
  unsigned short* STlo = (unsigned short*)(wsb + STLO_OFF);
  unsigned short* wgt  = (unsigned short*)(wsb + WGT_OFF);
  float* loss          = (float*)(wsb + LOSS_OFF);
  float* Z             = (float*)(wsb + Z_OFF);
  float* dinv          = (float*)(wsb + DINV_OFF);

  hipMemsetAsync(loss, 0, sizeof(float), stream);
  rowstats_kernel<<<NN, 256, 0, stream>>>(emb, A, Z, dinv);
  build_wt_kernel<<<NN, 256, 0, stream>>>(emb, A, delay, Z, dinv, WThi);
  init_s_kernel<<<NN, 128, 0, stream>>>(ca, iW1, ib1, iW2, ib2, SThi, STlo);
  build_wgt_kernel<<<32, 256, 0, stream>>>(Wm, Wsm, wgt);
  for (int k = 0; k < 12; ++k) {
    step_kernel<<<256, 512, 0, stream>>>(
        WThi, SThi, STlo, wgt, Wx, db, cb, cc, cd, ca,
        rW1, rb1, rW2, rb2, pW1, pb1, pW2, pb2, out, loss, k);
  }
  finalize_kernel<<<1, 1, 0, stream>>>(loss, out);
}

// Round 9
// 676.103 us; speedup vs baseline: 1.5353x; 1.5353x over previous
//
#include <hip/hip_runtime.h>
#include <cstddef>
#include <cstdint>

#define NN 1024
#define BB 16
#define NKNOTS 11

typedef __attribute__((ext_vector_type(8))) short short8_v;
typedef __attribute__((ext_vector_type(4))) float f32x4;
typedef __attribute__((ext_vector_type(8))) unsigned short ushort8_v;
typedef __attribute__((ext_vector_type(4))) unsigned short ushort4_v;
typedef __attribute__((ext_vector_type(4))) unsigned int uint4_v;

// ---- workspace byte offsets ----
#define WTHI_OFF  ((size_t)0)                         // 3 x 1M ushort = 6MB
#define STHI_OFF  ((size_t)6 << 20)                   // 4 x 1M ushort = 8MB
#define STLO_OFF  ((size_t)14 << 20)                  // 8MB
#define WGT_OFF   ((size_t)22 << 20)                  // 16KB bf16 swizzled W^T
#define SYNC_OFF  (((size_t)22 << 20) + 16384)        // 12 u32 sync counters
#define LOSS_OFF  (SYNC_OFF + 64)
#define Z_OFF     (LOSS_OFF + 256)
#define DINV_OFF  (Z_OFF + 4096)

// ---- scan kernel LDS layout (bytes) ----
// GEMM phase: 3 bufs x 32KB @ 0/32768/65536; buf = [A 16K][B 16K],
//   row 256B = 16 chunks of 16B, data chunk c stored at (c&8)|((c&7)^(row&7)).
// Epilogue overlay (after GEMM loop, before next staging):
#define AGGS   0        // f32 [64][68]
#define AGGH   17408    // bf16 plane [64 i][64 c], row 128B, chunk^=(row&7)
#define AGGL   25600
#define HH_    33792    // bf16 plane [64 i][64 c] of h_k
#define HL_    41984
#define HT32   50176    // packed hi/lo u32 plane [64 c][64 i]
#define REDS   66560    // reg-head partials (2KB)
#define PL1    68608    // pred layer1 (8KB)
#define WGT_L  98304    // persistent: swizzled W^T bf16 (16KB)

__device__ __forceinline__ unsigned short f2bf(float x) {
  unsigned int u = __float_as_uint(x);
  return (unsigned short)((u + 0x7FFFu + ((u >> 16) & 1u)) >> 16);
}
__device__ __forceinline__ float bf2f(unsigned short h) {
  return __uint_as_float(((unsigned int)h) << 16);
}
__device__ __forceinline__ void gload16(const void* g, void* l) {
  __builtin_amdgcn_global_load_lds(
      (const __attribute__((address_space(1))) unsigned int*)g,
      (__attribute__((address_space(3))) unsigned int*)l, 16, 0, 0);
}

// -------------------------------------------------------------------------
// Kernel 1: per-row softmax denominator Z[j] and degree rsqrt dinv[j]
// -------------------------------------------------------------------------
__global__ __launch_bounds__(256) void rowstats_kernel(
    const float* __restrict__ emb, const float* __restrict__ A,
    float* __restrict__ Z, float* __restrict__ dinv)
{
  const int j = blockIdx.x;
  const int tid = threadIdx.x;
  __shared__ float ej[64];
  __shared__ float r1[256], r2[256];
  if (tid < 64) ej[tid] = emb[j * 64 + tid];
  __syncthreads();
  float zs = 0.f, as = 0.f;
  for (int i = tid; i < NN; i += 256) {
    const float4* er = (const float4*)(emb + (size_t)i * 64);
    float dot = 0.f;
#pragma unroll
    for (int q = 0; q < 16; ++q) {
      float4 e = er[q];
      dot += e.x * ej[q * 4 + 0] + e.y * ej[q * 4 + 1] +
             e.z * ej[q * 4 + 2] + e.w * ej[q * 4 + 3];
    }
    zs += expf(fmaxf(dot, 0.f));
    as += A[(size_t)j * NN + i];
  }
  r1[tid] = zs; r2[tid] = as;
  __syncthreads();
  for (int s = 128; s > 0; s >>= 1) {
    if (tid < s) { r1[tid] += r1[tid + s]; r2[tid] += r2[tid + s]; }
    __syncthreads();
  }
  if (tid == 0) {
    Z[j] = r1[0];
    dinv[j] = rsqrtf(r2[0] + 1.0f);
  }
}

// -------------------------------------------------------------------------
// Kernel 2: WT[d][i][j] = (dsteps[j][i]==d) ? W[j][i] : 0, bf16
// -------------------------------------------------------------------------
__global__ __launch_bounds__(256) void build_wt_kernel(
    const float* __restrict__ emb, const float* __restrict__ A,
    const float* __restrict__ delay, const float* __restrict__ Z,
    const float* __restrict__ dinv, unsigned short* __restrict__ WThi)
{
  const int i = blockIdx.x;
  const int tid = threadIdx.x;
  __shared__ float ei[64];
  if (tid < 64) ei[tid] = emb[i * 64 + tid];
  __syncthreads();
  const float di = dinv[i];
  for (int j = tid; j < NN; j += 256) {
    const float4* er = (const float4*)(emb + (size_t)j * 64);
    float dot = 0.f;
#pragma unroll
    for (int q = 0; q < 16; ++q) {
      float4 e = er[q];
      dot += e.x * ei[q * 4 + 0] + e.y * ei[q * 4 + 1] +
             e.z * ei[q * 4 + 2] + e.w * ei[q * 4 + 3];
    }
    float sem = expf(fmaxf(dot, 0.f)) / Z[j];
    float aji = A[(size_t)j * NN + i] + ((i == j) ? 1.f : 0.f);
    float ac = sem + dinv[j] * di * aji;
    float w = (ac > 0.001f) ? ac : 0.f;
    float dl = fminf(fmaxf(delay[(size_t)j * NN + i], 0.f), 2.f);
    int dsv = (int)rintf(dl);
#pragma unroll
    for (int d0 = 0; d0 < 3; ++d0) {
      float v = (dsv == d0) ? w : 0.f;
      WThi[((size_t)d0 << 20) + (size_t)i * NN + j] = f2bf(v);
    }
  }
}

// -------------------------------------------------------------------------
// Kernel 3: history init -> transposed bf16 hi/lo ST slices 0,1
//   grid (NN, BB): block handles one (n, b).
// -------------------------------------------------------------------------
__global__ __launch_bounds__(128) void init_s_kernel(
    const float* __restrict__ ca, const float* __restrict__ W1,
    const float* __restrict__ b1, const float* __restrict__ W2,
    const float* __restrict__ b2,
    unsigned short* __restrict__ SThi, unsigned short* __restrict__ STlo)
{
  const int n = blockIdx.x;
  const int b = blockIdx.y;
  const int tid = threadIdx.x;
  __shared__ float l1[64];
  size_t cbase = ((size_t)(b * NN + n) * NKNOTS + 0) * 2;
  float x0 = ca[cbase + 0];
  float x1 = ca[cbase + 1];
  if (tid < 64)
    l1[tid] = fmaxf(x0 * W1[0 * 64 + tid] + x1 * W1[1 * 64 + tid] + b1[tid], 0.f);
  __syncthreads();
  float acc = b2[tid];
#pragma unroll 8
  for (int h = 0; h < 64; ++h) acc = fmaf(l1[h], W2[h * 128 + tid], acc);
  int t = tid >> 6, hh = tid & 63;
  size_t off = ((size_t)t << 20) + (size_t)(b * 64 + hh) * NN + n;
  unsigned short hv = f2bf(acc);
  SThi[off] = hv;
  STlo[off] = f2bf(acc - bf2f(hv));
}

// -------------------------------------------------------------------------
// Kernel 3b: W^T = [Wm;Ws]^T as bf16, pre-swizzled: row n (=h out), 128 k;
//            data chunk (kk>>3) stored at chunk (kk>>3)^(n&15).
// -------------------------------------------------------------------------
__global__ __launch_bounds__(256) void build_wgt_kernel(
    const float* __restrict__ Wm, const float* __restrict__ Wsm,
    unsigned short* __restrict__ wgt)
{
  int e = blockIdx.x * 256 + threadIdx.x;   // 8192 elems
  int n = e >> 7, kk = e & 127;
  float v = (kk < 64) ? Wm[kk * 64 + n] : Wsm[(kk - 64) * 64 + n];
  wgt[n * 128 + (((kk >> 3) ^ (n & 15)) << 3) + (kk & 7)] = f2bf(v);
}

// -------------------------------------------------------------------------
// Kernel 4: FUSED persistent scan — all 12 steps, grid-wide atomic barrier
//   between steps. 256 blocks (1/CU) x 512 thr; 8 waves = 2wr x 2wc x 2kh.
//   Per step: BK=128 3-buf counted-vmcnt MFMA GEMM + MFMA epilogue.
// -------------------------------------------------------------------------
__global__ __launch_bounds__(512, 2) void scan_kernel(
    const unsigned short* __restrict__ WThi,
    unsigned short* __restrict__ SThi, unsigned short* __restrict__ STlo,
    const unsigned short* __restrict__ wgt, unsigned int* __restrict__ syncc,
    const float* __restrict__ Wx, const float* __restrict__ db,
    const float* __restrict__ cb, const float* __restrict__ cc,
    const float* __restrict__ cd, const float* __restrict__ ca,
    const float* __restrict__ rW1, const float* __restrict__ rb1,
    const float* __restrict__ rW2, const float* __restrict__ rb2,
    const float* __restrict__ pW1, const float* __restrict__ pb1,
    const float* __restrict__ pW2, const float* __restrict__ pb2,
    float* __restrict__ out, float* __restrict__ loss)
{
  __shared__ __align__(16) char smem[114688];
  __shared__ float sWx[128];
  __shared__ float sdb[64];

  const int tid  = threadIdx.x;
  const int lane = tid & 63;
  const int w    = tid >> 6;            // wave 0..7
  const int bid  = blockIdx.x;
  // XCD-aware decode: each XCD owns 4 i_t x 8 b (A 1.5MB + B 3MB ~ L2)
  const int xcd = bid & 7, qq = bid >> 3;
  const int i_t = (xcd & 3) * 4 + (qq & 3);
  const int b   = (xcd >> 2) * 8 + (qq >> 2);
  const int i0 = i_t * 64, c0 = b * 64;

  const int wr = (w >> 1) & 1, wc = w & 1, kh = w >> 2;
  const int g = lane >> 4, l15 = lane & 15, sw = l15 & 7;

  if (tid < 128) sWx[tid] = Wx[tid];
  else if (tid < 192) sdb[tid - 128] = db[tid - 128];

  // stage swizzled W^T bf16 (16KB) once, persistent @WGT_L
  gload16(wgt + (size_t)tid * 8,        smem + WGT_L + tid * 16);
  gload16(wgt + 4096 + (size_t)tid * 8, smem + WGT_L + 8192 + tid * 16);

  // staging map: thread -> stored position tid (rows 0..31) and tid+512
  // (rows 32..63); stored chunk s = tid&15 holds data chunk (s&8)|((s&7)^(r&7))
  const int s_r = tid >> 4;                     // 0..31
  const int s_s = tid & 15;
  const int s_c = (s_s & 8) | ((s_s & 7) ^ (s_r & 7));
  // fragment byte offsets within a buffer
  const int rA0 = (wr * 32 + l15) * 256;
  const int rB0 = 16384 + (wc * 32 + l15) * 256;

  float (*aggS)[68] = (float (*)[68])(smem + AGGS);

  for (int k = 0; k < 12; ++k) {
    // ================= GEMM: K = 3 bins x 1024, BK=128, 24 iters ========
    f32x4 acc[2][2];
#pragma unroll
    for (int fr = 0; fr < 2; ++fr)
#pragma unroll
      for (int fc = 0; fc < 2; ++fc)
        acc[fr][fc] = (f32x4){0.f, 0.f, 0.f, 0.f};

    auto stage = [&](int t) {
      const int d = t >> 3, t8 = t & 7;
      int td = k + 1 - d; if (td < 0) td = 0;
      const unsigned short* Ab = WThi + ((size_t)d << 20) +
                                 (size_t)(i0 + s_r) * NN + t8 * 128;
      const unsigned short* Bb = SThi + ((size_t)(td & 3) << 20) +
                                 (size_t)(c0 + s_r) * NN + t8 * 128;
      char* dst = smem + (t % 3) * 32768;
      gload16(Ab + s_c * 8,                  dst + tid * 16);
      gload16(Ab + (size_t)32 * NN + s_c * 8, dst + 8192 + tid * 16);
      gload16(Bb + s_c * 8,                  dst + 16384 + tid * 16);
      gload16(Bb + (size_t)32 * NN + s_c * 8, dst + 24576 + tid * 16);
    };

    stage(0); stage(1);
    asm volatile("s_waitcnt vmcnt(4)" ::: "memory");   // buf0 (+wgt) landed
    __builtin_amdgcn_s_barrier();

    for (int t = 0; t < 24; ++t) {
      if (t < 22) stage(t + 2);        // overwrites buf (t-1)%3: safe (barrier'd)
      const char* bp = smem + (t % 3) * 32768;
#pragma unroll
      for (int ks = 0; ks < 2; ++ks) {
        const int s16 = ((kh << 3) | ((ks * 4 + g) ^ sw)) << 4;
        short8_v a0 = *(const short8_v*)(bp + rA0 + s16);
        short8_v a1 = *(const short8_v*)(bp + rA0 + 4096 + s16);
        short8_v b0 = *(const short8_v*)(bp + rB0 + s16);
        short8_v b1 = *(const short8_v*)(bp + rB0 + 4096 + s16);
        acc[0][0] = __builtin_amdgcn_mfma_f32_16x16x32_bf16(a0, b0, acc[0][0], 0, 0, 0);
        acc[0][1] = __builtin_amdgcn_mfma_f32_16x16x32_bf16(a0, b1, acc[0][1], 0, 0, 0);
        acc[1][0] = __builtin_amdgcn_mfma_f32_16x16x32_bf16(a1, b0, acc[1][0], 0, 0, 0);
        acc[1][1] = __builtin_amdgcn_mfma_f32_16x16x32_bf16(a1, b1, acc[1][1], 0, 0, 0);
      }
      __builtin_amdgcn_sched_barrier(0);
      if (t < 22) {
        asm volatile("s_waitcnt vmcnt(4)" ::: "memory");  // buf t+1 ready
        __builtin_amdgcn_s_barrier();
      } else if (t == 22) {
        asm volatile("s_waitcnt vmcnt(0)" ::: "memory");
        __builtin_amdgcn_s_barrier();
      }
    }

    // ---- merge kh halves into aggS (fp32) ----
    if (kh == 0) {
#pragma unroll
      for (int fr = 0; fr < 2; ++fr)
#pragma unroll
        for (int fc = 0; fc < 2; ++fc)
#pragma unroll
          for (int rr = 0; rr < 4; ++rr)
            aggS[wr * 32 + fr * 16 + g * 4 + rr][wc * 32 + fc * 16 + l15] = acc[fr][fc][rr];
    }
    __syncthreads();
    if (kh == 1) {
#pragma unroll
      for (int fr = 0; fr < 2; ++fr)
#pragma unroll
        for (int fc = 0; fc < 2; ++fc)
#pragma unroll
          for (int rr = 0; rr < 4; ++rr)
            aggS[wr * 32 + fr * 16 + g * 4 + rr][wc * 32 + fc * 16 + l15] += acc[fr][fc][rr];
    }
    __syncthreads();

    // ---- aggS -> bf16 hi/lo planes (chunk-swizzled) ----
    {
      const int row = tid >> 3, c8 = tid & 7;
      const float* src = &aggS[row][c8 * 8];
      ushort8_v H, L;
#pragma unroll
      for (int q = 0; q < 8; ++q) {
        float f = src[q];
        unsigned short hv = f2bf(f);
        H[q] = hv; L[q] = f2bf(f - bf2f(hv));
      }
      const int pos = (c8 ^ (row & 7)) << 4;
      *(ushort8_v*)(smem + AGGH + row * 128 + pos) = H;
      *(ushort8_v*)(smem + AGGL + row * 128 + pos) = L;
    }
    // ---- stage h_k (own tile, block-local) -> hH/hL planes ----
    {
      const int cl = tid >> 3, ich = (tid & 7) * 8;
      size_t off = ((size_t)((k + 1) & 3) << 20) + (size_t)(c0 + cl) * NN + (i0 + ich);
      ushort8_v h8 = *(const ushort8_v*)(SThi + off);
      ushort8_v l8 = *(const ushort8_v*)(STlo + off);
#pragma unroll
      for (int q = 0; q < 8; ++q) {
        int i = ich + q;
        int byo = i * 128 + ((((cl >> 3) ^ (i & 7))) << 4) + (cl & 7) * 2;
        *(unsigned short*)(smem + HH_ + byo) = h8[q];
        *(unsigned short*)(smem + HL_ + byo) = l8[q];
      }
    }
    __syncthreads();

    // ---- MFMA mini-GEMM: pre = [agg|h](64x128) @ W^T-frags (K=128) ----
    const int mr = w & 3, nc = w >> 2;   // 4 row-frags x 2 col-pairs
    f32x4 pacc[2];
    pacc[0] = (f32x4){0.f, 0.f, 0.f, 0.f};
    pacc[1] = (f32x4){0.f, 0.f, 0.f, 0.f};
#pragma unroll
    for (int ks = 0; ks < 4; ++ks) {
      const int base = (ks < 2) ? AGGH : HH_;
      const int ks2 = ks & 1;
      const int cxa = ((ks2 * 4 + g) ^ (l15 & 7)) << 4;
      const char* ra = smem + base + (mr * 16 + l15) * 128 + cxa;
      short8_v aH = *(const short8_v*)ra;
      short8_v aL = *(const short8_v*)(ra + 8192);
#pragma unroll
      for (int fc = 0; fc < 2; ++fc) {
        const int n = (nc * 2 + fc) * 16 + l15;
        const int cxb = ((ks * 4 + g) ^ l15) << 4;
        short8_v bv = *(const short8_v*)(smem + WGT_L + n * 256 + cxb);
        pacc[fc] = __builtin_amdgcn_mfma_f32_16x16x32_bf16(aH, bv, pacc[fc], 0, 0, 0);
        pacc[fc] = __builtin_amdgcn_mfma_f32_16x16x32_bf16(aL, bv, pacc[fc], 0, 0, 0);
      }
    }
    __syncthreads();

    // ---- dx@Wx + bias, tanh; write ST ring + packed hT32 plane ----
    const int ksp = (k < 11) ? k : 10;
    float hn[2][4];
#pragma unroll
    for (int rr = 0; rr < 4; ++rr) {
      int iG = i0 + mr * 16 + g * 4 + rr;
      size_t cbase = ((size_t)(b * NN + iG) * NKNOTS + ksp) * 2;
      float dx0 = cb[cbase + 0], dx1 = cb[cbase + 1];
      if (k == 11) {   // frac = 1: der = b + 2c + 3d
        dx0 += 2.f * cc[cbase + 0] + 3.f * cd[cbase + 0];
        dx1 += 2.f * cc[cbase + 1] + 3.f * cd[cbase + 1];
      }
#pragma unroll
      for (int fc = 0; fc < 2; ++fc) {
        int hcol = (nc * 2 + fc) * 16 + l15;
        float pre = pacc[fc][rr] + dx0 * sWx[hcol] + dx1 * sWx[64 + hcol] + sdb[hcol];
        hn[fc][rr] = tanhf(pre);
      }
    }
#pragma unroll
    for (int fc = 0; fc < 2; ++fc) {
      int hcol = (nc * 2 + fc) * 16 + l15;
      int iG0 = i0 + mr * 16 + g * 4;
      size_t off2 = ((size_t)((k + 2) & 3) << 20) + (size_t)(c0 + hcol) * NN + iG0;
      ushort4_v H4, L4;
      uint4_v pk;
#pragma unroll
      for (int rr = 0; rr < 4; ++rr) {
        unsigned short hv = f2bf(hn[fc][rr]);
        unsigned short lv = f2bf(hn[fc][rr] - bf2f(hv));
        H4[rr] = hv; L4[rr] = lv;
        pk[rr] = ((unsigned int)hv << 16) | lv;
      }
      *(ushort4_v*)(SThi + off2) = H4;
      *(ushort4_v*)(STlo + off2) = L4;
      const int ci = mr * 4 + g;           // i-chunk (4 i's = 16B)
      *(uint4_v*)(smem + HT32 + hcol * 256 + ((ci ^ (hcol & 15)) << 4)) = pk;
    }
    __syncthreads();

    // ---- reg head + Huber (h_new from hT32 plane) ----
    {
      const int ii = tid & 63, mg4 = (tid >> 6) * 4;
      float s0 = rb1[mg4], s1 = rb1[mg4 + 1], s2 = rb1[mg4 + 2], s3 = rb1[mg4 + 3];
#pragma unroll 8
      for (int h = 0; h < 64; ++h) {
        unsigned int v = *(const unsigned int*)(smem + HT32 + h * 256 +
                           ((((ii >> 2) ^ (h & 15))) << 4) + (ii & 3) * 4);
        float f = bf2f((unsigned short)(v >> 16)) + bf2f((unsigned short)(v & 0xffff));
        float4 wv = *(const float4*)(rW1 + h * 32 + mg4);
        s0 = fmaf(f, wv.x, s0); s1 = fmaf(f, wv.y, s1);
        s2 = fmaf(f, wv.z, s2); s3 = fmaf(f, wv.w, s3);
      }
      float4 r2v = *(const float4*)(rW2 + mg4);
      float rp = fmaxf(s0, 0.f) * r2v.x + fmaxf(s1, 0.f) * r2v.y +
                 fmaxf(s2, 0.f) * r2v.z + fmaxf(s3, 0.f) * r2v.w;
      float* redS = (float*)(smem + REDS);
      redS[(tid >> 6) * 64 + ii] = rp;
      __syncthreads();
      if (tid < 64) {
        float rv = rb2[0];
#pragma unroll
        for (int m = 0; m < 8; ++m) rv += redS[m * 64 + tid];
        int iG = i0 + tid;
        size_t tb = ((size_t)(b * NN + iG) * NKNOTS + ksp) * 2;
        float tgt = ca[tb];
        if (k == 11) tgt += cb[tb] + cc[tb] + cd[tb];   // frac=1: a+b+c+d
        float dv = rv - tgt;
        float ad = fabsf(dv);
        float hub = (ad < 1.f) ? 0.5f * dv * dv : (ad - 0.5f);
        hub += __shfl_down(hub, 32);
        hub += __shfl_down(hub, 16);
        hub += __shfl_down(hub, 8);
        hub += __shfl_down(hub, 4);
        hub += __shfl_down(hub, 2);
        hub += __shfl_down(hub, 1);
        if (tid == 0) atomicAdd(loss, hub);
      }
    }

    // ---- pred head (k == 11 only) ----
    if (k == 11) {
      __syncthreads();
      const int ii = tid & 63, mg4 = (tid >> 6) * 4;
      float s0 = pb1[mg4], s1 = pb1[mg4 + 1], s2 = pb1[mg4 + 2], s3 = pb1[mg4 + 3];
#pragma unroll 8
      for (int h = 0; h < 64; ++h) {
        unsigned int v = *(const unsigned int*)(smem + HT32 + h * 256 +
                           ((((ii >> 2) ^ (h & 15))) << 4) + (ii & 3) * 4);
        float f = bf2f((unsigned short)(v >> 16)) + bf2f((unsigned short)(v & 0xffff));
        float4 wv = *(const float4*)(pW1 + h * 32 + mg4);
        s0 = fmaf(f, wv.x, s0); s1 = fmaf(f, wv.y, s1);
        s2 = fmaf(f, wv.z, s2); s3 = fmaf(f, wv.w, s3);
      }
      float* pl1 = (float*)(smem + PL1);
      pl1[ii * 32 + mg4 + 0] = fmaxf(s0, 0.f);
      pl1[ii * 32 + mg4 + 1] = fmaxf(s1, 0.f);
      pl1[ii * 32 + mg4 + 2] = fmaxf(s2, 0.f);
      pl1[ii * 32 + mg4 + 3] = fmaxf(s3, 0.f);
      __syncthreads();
#pragma unroll
      for (int rep = 0; rep < 2; ++rep) {
        int idxp = tid + rep * 512;
        if (idxp < 768) {
          int i_ = idxp / 12, o = idxp % 12;
          float s = pb2[o];
#pragma unroll
          for (int m = 0; m < 32; ++m) s = fmaf(pl1[i_ * 32 + m], pW2[m * 12 + o], s);
          out[((size_t)b * NN + (i0 + i_)) * 12 + o] = s;
        }
      }
    }

    // ---- grid-wide barrier: step k writes -> step k+1 reads ----
    asm volatile("s_waitcnt vmcnt(0)" ::: "memory");  // drain stores/loads
    __syncthreads();
    if (tid == 0) {
      __threadfence();                      // release (L2 writeback)
      atomicAdd(&syncc[k], 1u);
      while (atomicAdd(&syncc[k], 0u) < 256u) __builtin_amdgcn_s_sleep(2);
      __threadfence();                      // acquire (invalidate stale)
    }
    __syncthreads();
  }
}

__global__ void finalize_kernel(const float* __restrict__ loss, float* __restrict__ out)
{
  out[196608] = loss[0] * (1.0f / 196608.0f);
}

// -------------------------------------------------------------------------
extern "C" void kernel_launch(void* const* d_in, const int* in_sizes, int n_in,
                              void* d_out, int out_size, void* d_ws, size_t ws_size,
                              hipStream_t stream)
{
  const float* A     = (const float*)d_in[0];
  const float* delay = (const float*)d_in[1];
  const float* ca    = (const float*)d_in[2];
  const float* cb    = (const float*)d_in[3];
  const float* cc    = (const float*)d_in[4];
  const float* cd    = (const float*)d_in[5];
  const float* emb   = (const float*)d_in[6];
  const float* iW1   = (const float*)d_in[7];
  const float* ib1   = (const float*)d_in[8];
  const float* iW2   = (const float*)d_in[9];
  const float* ib2   = (const float*)d_in[10];
  const float* Wm    = (const float*)d_in[11];
  const float* Wsm   = (const float*)d_in[12];
  const float* Wx    = (const float*)d_in[13];
  const float* db    = (const float*)d_in[14];
  const float* rW1   = (const float*)d_in[15];
  const float* rb1   = (const float*)d_in[16];
  const float* rW2   = (const float*)d_in[17];
  const float* rb2   = (const float*)d_in[18];
  const float* pW1   = (const float*)d_in[19];
  const float* pb1   = (const float*)d_in[20];
  const float* pW2   = (const float*)d_in[21];
  const float* pb2   = (const float*)d_in[22];

  char* wsb = (char*)d_ws;
  float* out = (float*)d_out;
  unsigned short* WThi = (unsigned short*)(wsb + WTHI_OFF);
  unsigned short* SThi = (unsigned short*)(wsb + STHI_OFF);
  unsigned short* STlo = (unsigned short*)(wsb + STLO_OFF);
  unsigned short* wgt  = (unsigned short*)(wsb + WGT_OFF);
  unsigned int* syncc  = (unsigned int*)(wsb + SYNC_OFF);
  float* loss          = (float*)(wsb + LOSS_OFF);
  float* Z             = (float*)(wsb + Z_OFF);
  float* dinv          = (float*)(wsb + DINV_OFF);

  hipMemsetAsync(syncc, 0, 128, stream);   // sync counters + loss
  rowstats_kernel<<<NN, 256, 0, stream>>>(emb, A, Z, dinv);
  build_wt_kernel<<<NN, 256, 0, stream>>>(emb, A, delay, Z, dinv, WThi);
  init_s_kernel<<<dim3(NN, BB), 128, 0, stream>>>(ca, iW1, ib1, iW2, ib2, SThi, STlo);
  build_wgt_kernel<<<32, 256, 0, stream>>>(Wm, Wsm, wgt);
  scan_kernel<<<256, 512, 0, stream>>>(
      WThi, SThi, STlo, wgt, syncc, Wx, db, cb, cc, cd, ca,
      rW1, rb1, rW2, rb2, pW1, pb1, pW2, pb2, out, loss);
  finalize_kernel<<<1, 1, 0, stream>>>(loss, out);
}